// Round 1
// baseline (88.582 us; speedup 1.0000x reference)
//
#include <hip/hip_runtime.h>

// Problem constants (fixed by setup_inputs)
#define BB 2
#define CC 32
#define HH 128
#define WW 256
#define DD 48
#define HW (HH * WW)      // 32768
#define WT 128            // w-tile per block (2 tiles per row)
#define HALO 64           // left halo of y needed for shifts up to 64
#define YR (HALO + WT)    // 192 floats per staged y row

// cost[b,d,h,w] = (1/C) * sum_c x[b,c,h,w] * bilinear(y at w-disp)
// Factored: corr[s][w] = sum_c x[c,w]*y[c,w-s]  (s = 0..64, zeros pad)
//           out = ((1-fx)*corr[i0] + fx*corr[i0-1]) / C,  i0=ceil(disp), fx=i0-disp
//
// Restructure vs previous version:
//  - WT=128 tiles: LDS 74.2 KB -> 2 blocks/CU (cross-block phase overlap)
//  - P2: 16 half-waves x 4-shift groups (all lanes busy, was 9/16 waves)
//  - disp prefetched to registers during P1 (latency hidden under staging)
//  - global->LDS async staging (global_load_lds, width 16) where linear

__device__ __forceinline__ void ldg16_lds(const float* g, float* l) {
  __builtin_amdgcn_global_load_lds(
      (const __attribute__((address_space(1))) void*)g,
      (__attribute__((address_space(3))) void*)l, 16, 0, 0);
}

__global__ __launch_bounds__(512, 4) void cost_volume_kernel(
    const float* __restrict__ x, const float* __restrict__ y,
    const float* __restrict__ disp, float* __restrict__ out) {
  __shared__ float xs[CC * WT];    // 16 KB
  __shared__ float ys[CC * YR];    // 24 KB (first HALO floats of row may be zero pad)
  __shared__ float corr[65 * WT];  // 33.25 KB

  const int bx = blockIdx.x;
  const int tile = bx & 1;             // which half of the row
  const int h = (bx >> 1) & (HH - 1);
  const int b = bx >> 8;
  const int wt0 = tile << 7;           // 0 or 128
  const int tid = threadIdx.x;

  const int gbase = (b * CC * HH + h) * WW;  // + c*HW + w

  // ---------------- Phase 1: stage xs, ys; prefetch disp into regs ----------
  // xs: 1024 float4, LDS-linear in thread order -> async direct-to-LDS
#pragma unroll
  for (int k = 0; k < 2; ++k) {
    int t4 = tid + (k << 9);
    int c = t4 >> 5;
    int w4 = (t4 & 31) << 2;
    ldg16_lds(x + gbase + c * HW + wt0 + w4, &xs[t4 << 2]);
  }
  if (tile) {
    // right tile: full 192-float rows are in-bounds (global w in [64,256))
#pragma unroll
    for (int k = 0; k < 3; ++k) {
      int t4 = tid + (k << 9);          // 0..1535
      int c = t4 / 48;                  // 48 float4 per row
      int j4 = t4 - c * 48;
      ldg16_lds(y + gbase + c * HW + (wt0 - HALO) + (j4 << 2), &ys[t4 << 2]);
    }
  } else {
    // left tile: j < HALO maps to global w < 0 -> zeros; reg-stage w/ predicate
#pragma unroll
    for (int k = 0; k < 3; ++k) {
      int t4 = tid + (k << 9);
      int c = t4 / 48;
      int j = (t4 - c * 48) << 2;       // 0..188
      float4 v = make_float4(0.f, 0.f, 0.f, 0.f);
      if (j >= HALO) v = *(const float4*)(y + gbase + c * HW + (j - HALO));
      *(float4*)&ys[c * YR + j] = v;
    }
  }
  // disp prefetch: 12 scalars/thread; loads complete under the P1 barrier drain
  const int dobase = (b * DD * HH + h) * WW + wt0;  // disp/out share geometry
  float dreg[12];
#pragma unroll
  for (int k = 0; k < 12; ++k) {
    int idx = tid + (k << 9);
    int d = idx >> 7;
    int w = idx & (WT - 1);
    dreg[k] = disp[dobase + d * HW + w];
  }
  __syncthreads();

  // ---------------- Phase 2: corr[s][w] = sum_c xs[c][w]*ys[c][w+HALO-s] ----
  // 16 half-waves; half-wave g owns shifts 4g..4g+3 over all 128 w.
  const int lane = tid & 63;
  const int wid = tid >> 6;          // 0..7
  const int half = lane >> 5;
  const int w0 = (lane & 31) << 2;   // 0..124, each lane owns 4 consecutive w
  const int g = wid + (half << 3);   // 0..15
  const int A = HALO + w0 - (g << 2) - 4;  // float4-aligned window base

  float acc[4][4];
#pragma unroll
  for (int sl = 0; sl < 4; ++sl)
#pragma unroll
    for (int wj = 0; wj < 4; ++wj) acc[sl][wj] = 0.f;
  float a64[4] = {0.f, 0.f, 0.f, 0.f};  // s=64 row (wave 0 only)

#pragma unroll 4
  for (int c = 0; c < CC; ++c) {
    float4 xv = *(const float4*)&xs[c * WT + w0];       // broadcast across halves
    float4 wv0 = *(const float4*)&ys[c * YR + A];       // window [A, A+8)
    float4 wv1 = *(const float4*)&ys[c * YR + A + 4];
    float win[8] = {wv0.x, wv0.y, wv0.z, wv0.w, wv1.x, wv1.y, wv1.z, wv1.w};
    float xr[4] = {xv.x, xv.y, xv.z, xv.w};
#pragma unroll
    for (int sl = 0; sl < 4; ++sl)
#pragma unroll
      for (int wj = 0; wj < 4; ++wj)
        acc[sl][wj] = fmaf(xr[wj], win[4 + wj - sl], acc[sl][wj]);
    if (wid == 0) {  // s=64: ys index = w0+wj (both halves redundantly, broadcast)
      float4 yv = *(const float4*)&ys[c * YR + w0];
      a64[0] = fmaf(xr[0], yv.x, a64[0]);
      a64[1] = fmaf(xr[1], yv.y, a64[1]);
      a64[2] = fmaf(xr[2], yv.z, a64[2]);
      a64[3] = fmaf(xr[3], yv.w, a64[3]);
    }
  }
#pragma unroll
  for (int sl = 0; sl < 4; ++sl)
    *(float4*)&corr[((g << 2) + sl) * WT + w0] =
        make_float4(acc[sl][0], acc[sl][1], acc[sl][2], acc[sl][3]);
  if (wid == 0 && half == 0)
    *(float4*)&corr[64 * WT + w0] = make_float4(a64[0], a64[1], a64[2], a64[3]);
  __syncthreads();

  // ---------------- Phase 3: per-output lerp (disp already in regs) ---------
  // Lanes span consecutive w -> corr reads hit bank (w&31): conflict-free.
  const float inv_c = 1.0f / (float)CC;
  float* obase = out + dobase;
#pragma unroll
  for (int k = 0; k < 12; ++k) {
    int idx = tid + (k << 9);
    int d = idx >> 7;
    int w = idx & (WT - 1);
    float dv = dreg[k];
    float s0f = ceilf(dv);
    int i0 = (int)s0f;
    float fx = s0f - dv;              // in [0,1)
    int i1 = (i0 > 0) ? i0 - 1 : 0;   // i0==0 => fx==0, weight-0 read
    float c0 = corr[i0 * WT + w];
    float c1 = corr[i1 * WT + w];
    obase[d * HW + w] = (c0 + fx * (c1 - c0)) * inv_c;
  }
}

extern "C" void kernel_launch(void* const* d_in, const int* in_sizes, int n_in,
                              void* d_out, int out_size, void* d_ws, size_t ws_size,
                              hipStream_t stream) {
  const float* x = (const float*)d_in[0];
  const float* y = (const float*)d_in[1];
  const float* disp = (const float*)d_in[2];
  float* out = (float*)d_out;
  cost_volume_kernel<<<BB * HH * 2, 512, 0, stream>>>(x, y, disp, out);
}

// Round 2
// 85.854 us; speedup vs baseline: 1.0318x; 1.0318x over previous
//
#include <hip/hip_runtime.h>

// Problem constants (fixed by setup_inputs)
#define BB 2
#define CC 32
#define HH 128
#define WW 256
#define DD 48
#define HW (HH * WW)      // 32768
#define WT 128            // w-tile per block (2 tiles per row)
#define HALO 64           // left halo of y needed for shifts up to 64
#define YR (HALO + WT)    // 192 floats per staged y row

// cost[b,d,h,w] = (1/C) * sum_c x[b,c,h,w] * bilinear(y at w-disp)
// Factored: corr[s][w] = sum_c x[c,w]*y[c,w-s]  (s = 0..64, zeros pad)
//           out = ((1-fx)*corr[i0] + fx*corr[i0-1]) / C,  i0=ceil(disp), fx=i0-disp
//
// Round-2 changes vs round-1:
//  - P2: 8-shift teams (32 lanes own 8 shifts x 4 w) -> 2 B/FMA LDS intensity
//    (was 3 B/FMA with 4-shift teams); ~30% less LDS-pipe traffic. Teams 9..15
//    idle in P2 -> their slots feed the co-resident sibling block (2 blocks/CU).
//  - disp loads issued AFTER the P2 accumulator dies (pre-barrier): no registers
//    held across the high-pressure loop -> no spill risk under the 128-VGPR cap;
//    HBM latency drains under the barrier.

__device__ __forceinline__ void ldg16_lds(const float* g, float* l) {
  __builtin_amdgcn_global_load_lds(
      (const __attribute__((address_space(1))) void*)g,
      (__attribute__((address_space(3))) void*)l, 16, 0, 0);
}

__global__ __launch_bounds__(512, 4) void cost_volume_kernel(
    const float* __restrict__ x, const float* __restrict__ y,
    const float* __restrict__ disp, float* __restrict__ out) {
  __shared__ float xs[CC * WT];    // 16 KB
  __shared__ float ys[CC * YR];    // 24 KB (first HALO floats may be zero pad)
  __shared__ float corr[65 * WT];  // 33.25 KB   (total 74.2 KB -> 2 blocks/CU)

  const int bx = blockIdx.x;
  const int tile = bx & 1;             // which half of the row
  const int h = (bx >> 1) & (HH - 1);
  const int b = bx >> 8;
  const int wt0 = tile << 7;           // 0 or 128
  const int tid = threadIdx.x;

  const int gbase = (b * CC * HH + h) * WW;  // + c*HW + w

  // ---------------- Phase 1: stage xs, ys --------------------------------
#pragma unroll
  for (int k = 0; k < 2; ++k) {
    int t4 = tid + (k << 9);
    int c = t4 >> 5;
    int w4 = (t4 & 31) << 2;
    ldg16_lds(x + gbase + c * HW + wt0 + w4, &xs[t4 << 2]);
  }
  if (tile) {
    // right tile: full 192-float rows in-bounds (global w in [64,256))
#pragma unroll
    for (int k = 0; k < 3; ++k) {
      int t4 = tid + (k << 9);          // 0..1535
      int c = t4 / 48;                  // 48 float4 per row
      int j4 = t4 - c * 48;
      ldg16_lds(y + gbase + c * HW + (wt0 - HALO) + (j4 << 2), &ys[t4 << 2]);
    }
  } else {
    // left tile: j < HALO maps to global w < 0 -> zeros; reg-stage w/ predicate
#pragma unroll
    for (int k = 0; k < 3; ++k) {
      int t4 = tid + (k << 9);
      int c = t4 / 48;
      int j = (t4 - c * 48) << 2;       // 0..188
      float4 v = make_float4(0.f, 0.f, 0.f, 0.f);
      if (j >= HALO) v = *(const float4*)(y + gbase + c * HW + (j - HALO));
      *(float4*)&ys[c * YR + j] = v;
    }
  }
  __syncthreads();

  // ---------------- Phase 2: corr[s][w] = sum_c xs[c][w]*ys[c][w+HALO-s] --
  // 32-lane teams: team t in 0..7 owns shifts 8t..8t+7 over all 128 w
  // (4 w per lane); team 8 does s=64; teams 9..15 idle (feed sibling block).
  const int team = tid >> 5;           // 0..15
  const int tlane = tid & 31;
  const int w0 = tlane << 2;           // 0..124

  if (team < 8) {
    float acc[8][4];
#pragma unroll
    for (int sl = 0; sl < 8; ++sl)
#pragma unroll
      for (int wj = 0; wj < 4; ++wj) acc[sl][wj] = 0.f;

    // ys index needed: HALO + (w0+wj) - (8t+sl), wj 0..3, sl 0..7
    //   = [base-7, base+3], base = HALO + w0 - 8t.  Aligned A = base - 8 >= 0.
    const int A = HALO + w0 - (team << 3) - 8;
#pragma unroll 4
    for (int c = 0; c < CC; ++c) {
      float4 xv = *(const float4*)&xs[c * WT + w0];   // broadcast across halves
      const float* yrow = &ys[c * YR];
      float4 wv0 = *(const float4*)&yrow[A];
      float4 wv1 = *(const float4*)&yrow[A + 4];
      float4 wv2 = *(const float4*)&yrow[A + 8];
      float win[12] = {wv0.x, wv0.y, wv0.z, wv0.w, wv1.x, wv1.y,
                       wv1.z, wv1.w, wv2.x, wv2.y, wv2.z, wv2.w};
      float xr[4] = {xv.x, xv.y, xv.z, xv.w};
#pragma unroll
      for (int sl = 0; sl < 8; ++sl)
#pragma unroll
        for (int wj = 0; wj < 4; ++wj)
          acc[sl][wj] = fmaf(xr[wj], win[8 + wj - sl], acc[sl][wj]);
    }
#pragma unroll
    for (int sl = 0; sl < 8; ++sl)
      *(float4*)&corr[((team << 3) + sl) * WT + w0] =
          make_float4(acc[sl][0], acc[sl][1], acc[sl][2], acc[sl][3]);
  } else if (team == 8) {
    // s = 64: ys index = HALO + w - 64 = w
    float a64[4] = {0.f, 0.f, 0.f, 0.f};
#pragma unroll 4
    for (int c = 0; c < CC; ++c) {
      float4 xv = *(const float4*)&xs[c * WT + w0];
      float4 yv = *(const float4*)&ys[c * YR + w0];
      a64[0] = fmaf(xv.x, yv.x, a64[0]);
      a64[1] = fmaf(xv.y, yv.y, a64[1]);
      a64[2] = fmaf(xv.z, yv.z, a64[2]);
      a64[3] = fmaf(xv.w, yv.w, a64[3]);
    }
    *(float4*)&corr[64 * WT + w0] = make_float4(a64[0], a64[1], a64[2], a64[3]);
  }

  // disp prefetch: issued after acc is dead, drains under the barrier.
  const int dobase = (b * DD * HH + h) * WW + wt0;  // disp/out share geometry
  float dreg[12];
#pragma unroll
  for (int k = 0; k < 12; ++k) {
    int idx = tid + (k << 9);
    int d = idx >> 7;
    int w = idx & (WT - 1);
    dreg[k] = disp[dobase + d * HW + w];
  }
  __syncthreads();

  // ---------------- Phase 3: per-output lerp ------------------------------
  // Lanes span consecutive w -> corr reads hit bank (w&31): conflict-free.
  const float inv_c = 1.0f / (float)CC;
  float* obase = out + dobase;
#pragma unroll
  for (int k = 0; k < 12; ++k) {
    int idx = tid + (k << 9);
    int d = idx >> 7;
    int w = idx & (WT - 1);
    float dv = dreg[k];
    float s0f = ceilf(dv);
    int i0 = (int)s0f;
    float fx = s0f - dv;              // in [0,1)
    int i1 = (i0 > 0) ? i0 - 1 : 0;   // i0==0 => fx==0, weight-0 read
    float c0 = corr[i0 * WT + w];
    float c1 = corr[i1 * WT + w];
    obase[d * HW + w] = (c0 + fx * (c1 - c0)) * inv_c;
  }
}

extern "C" void kernel_launch(void* const* d_in, const int* in_sizes, int n_in,
                              void* d_out, int out_size, void* d_ws, size_t ws_size,
                              hipStream_t stream) {
  const float* x = (const float*)d_in[0];
  const float* y = (const float*)d_in[1];
  const float* disp = (const float*)d_in[2];
  float* out = (float*)d_out;
  cost_volume_kernel<<<BB * HH * 2, 512, 0, stream>>>(x, y, disp, out);
}